// Round 3
// baseline (769.445 us; speedup 1.0000x reference)
//
#include <hip/hip_runtime.h>

#define EPSF 1e-6f

// ---------------- wave helpers ----------------
__device__ __forceinline__ float wave_max(float v) {
    #pragma unroll
    for (int m = 32; m; m >>= 1) v = fmaxf(v, __shfl_xor(v, m, 64));
    return v;
}
__device__ __forceinline__ float wave_sum(float v) {
    #pragma unroll
    for (int m = 32; m; m >>= 1) v += __shfl_xor(v, m, 64);
    return v;
}
__device__ __forceinline__ float lane_bcast(float v, int src) {
    return __int_as_float(__builtin_amdgcn_readlane(__float_as_int(v), src));
}

// ---------------- K1: depthwise 4x4 stride-4 downsample ----------------
// x [4,128,256,256] -> xd [4,128,64,64]
__global__ void k_down(const float* __restrict__ x, const float* __restrict__ wd,
                       float* __restrict__ xd) {
    int idx = blockIdx.x * 256 + threadIdx.x;   // 4*128*64*64 = 2097152
    int ow = idx & 63;
    int oh = (idx >> 6) & 63;
    int c  = (idx >> 12) & 127;
    int n  = idx >> 19;
    const float* xp = x + ((((size_t)n * 128 + c) * 256 + oh * 4) * 256) + ow * 4;
    const float* w  = wd + c * 16;
    float acc = 0.f;
    #pragma unroll
    for (int r = 0; r < 4; ++r) {
        float4 v = *reinterpret_cast<const float4*>(xp + (size_t)r * 256);
        acc += w[r*4+0]*v.x + w[r*4+1]*v.y + w[r*4+2]*v.z + w[r*4+3]*v.w;
    }
    xd[idx] = acc;
}

// ---------------- K2: 1x1 convs (theta / phi_u / g_u) ----------------
// xd [n,128,4096] -> out [n,64,4096];  grid (16 p-blocks, 4 n, 3 which)
__global__ void k_conv(const float* __restrict__ xd,
                       const float* __restrict__ w0, const float* __restrict__ b0,
                       const float* __restrict__ w1, const float* __restrict__ b1,
                       const float* __restrict__ w2, const float* __restrict__ b2,
                       float* __restrict__ theta, float* __restrict__ phi_u,
                       float* __restrict__ g_u) {
    __shared__ float wl[64 * 128];
    int which = blockIdx.z;
    const float* w = (which == 0) ? w0 : (which == 1) ? w1 : w2;
    const float* b = (which == 0) ? b0 : (which == 1) ? b1 : b2;
    float* out = (which == 0) ? theta : (which == 1) ? phi_u : g_u;
    for (int i = threadIdx.x; i < 64 * 128; i += 256) wl[i] = w[i];
    __syncthreads();
    int n = blockIdx.y;
    int p = blockIdx.x * 256 + threadIdx.x;
    const float* xp = xd + (size_t)n * 128 * 4096 + p;
    float acc[64];
    #pragma unroll
    for (int o = 0; o < 64; ++o) acc[o] = b[o];
    for (int c = 0; c < 128; ++c) {
        float xv = xp[(size_t)c * 4096];
        #pragma unroll
        for (int o = 0; o < 64; ++o) acc[o] = fmaf(wl[o * 128 + c], xv, acc[o]);
    }
    float* op = out + (size_t)n * 64 * 4096 + p;
    #pragma unroll
    for (int o = 0; o < 64; ++o) op[(size_t)o * 4096] = acc[o];
}

// ---------------- K3: 2x2 maxpool (phi stays [c][j]; g transposed to [j][c]) ----------------
__global__ void k_pool(const float* __restrict__ phi_u, const float* __restrict__ g_u,
                       float* __restrict__ phi, float* __restrict__ g_t) {
    int idx = blockIdx.x * 256 + threadIdx.x;   // 4*64*1024 = 262144
    int q = idx & 1023;
    int o = (idx >> 10) & 63;
    int n = idx >> 16;
    int qh = q >> 5, qw = q & 31;
    const float* sel = (blockIdx.y == 0) ? phi_u : g_u;
    const float* sp = sel + (((size_t)n * 64 + o) * 4096) + (qh * 2) * 64 + qw * 2;
    float m = fmaxf(fmaxf(sp[0], sp[1]), fmaxf(sp[64], sp[65]));
    if (blockIdx.y == 0) phi[idx] = m;
    else g_t[((size_t)n * 1024 + q) * 64 + o] = m;
}

// ---------------- K4: bilinear depth samples d1 (64x64), d2 (32x32) ----------------
__global__ void k_d12(const float* __restrict__ depth, float* __restrict__ d1,
                      float* __restrict__ d2) {
    int idx = blockIdx.x * 256 + threadIdx.x;
    const int T1 = 4 * 4096;
    bool is1 = idx < T1;
    int e = is1 ? idx : idx - T1;
    if (!is1 && e >= 4 * 1024) return;
    int n, oh, ow;
    float fy, fx;
    if (is1) { n = e >> 12; oh = (e >> 6) & 63; ow = e & 63;
               fy = (oh * 255.f) / 63.f;  fx = (ow * 255.f) / 63.f; }
    else     { n = e >> 10; oh = (e >> 5) & 31; ow = e & 31;
               fy = (oh * 255.f) / 31.f;  fx = (ow * 255.f) / 31.f; }
    int y0 = (int)floorf(fy); int y1 = min(y0 + 1, 255);
    int x0 = (int)floorf(fx); int x1 = min(x0 + 1, 255);
    float wy = fy - (float)y0, wx = fx - (float)x0;
    const float* dp = depth + (size_t)n * 65536;
    float v00 = dp[y0 * 256 + x0], v01 = dp[y0 * 256 + x1];
    float v10 = dp[y1 * 256 + x0], v11 = dp[y1 * 256 + x1];
    float r0 = v00 * (1.f - wx) + v01 * wx;
    float r1 = v10 * (1.f - wx) + v11 * wx;
    float v  = r0 * (1.f - wy) + r1 * wy;
    if (is1) d1[e] = v; else d2[e] = v;
}

// ---------------- K5: fused attention (v2: low-LDS, readlane GEMM2) ----------------
// theta [n,64,4096], phi [n,64,1024], g_t [n,1024,64], d1 [n,4096], d2 [n,1024]
// -> y_t [n,64,4096]
// 256 thr = 4 waves; 16 rows/block (4/wave); grid (256,4)
// LDS = 32KB phi chunk + 4KB theta + 4KB d2 = 40960 B; VGPR cap via bounds(256,3)
// -> 3 waves/SIMD vs 1 in v1.
#define ROWS 16
#define RPW  4
#define CCH  8
__global__ __launch_bounds__(256, 3)
void k_attn(const float* __restrict__ theta, const float* __restrict__ phi,
            const float* __restrict__ g_t, const float* __restrict__ d1,
            const float* __restrict__ d2, float* __restrict__ y_t) {
    __shared__ float pbuf[CCH * 1024];   // 32KB phi chunk
    __shared__ float thl[64 * ROWS];     // theta tile [c][r]
    __shared__ float d2l[1024];

    int n = blockIdx.y;
    int row0 = blockIdx.x * ROWS;
    int tid = threadIdx.x;
    int lane = tid & 63;
    int wv = tid >> 6;

    for (int i = tid; i < ROWS * 64; i += 256) {
        int r = i & (ROWS - 1); int c = i >> 4;
        thl[c * ROWS + r] = theta[((size_t)n * 64 + c) * 4096 + row0 + r];
    }
    for (int i = tid; i < 1024; i += 256) d2l[i] = d2[n * 1024 + i];

    float acc[RPW][16];
    #pragma unroll
    for (int r = 0; r < RPW; ++r)
        #pragma unroll
        for (int k = 0; k < 16; ++k) acc[r][k] = 0.f;

    // ---- GEMM1: a[r][j] = theta_row . phi_col ----
    for (int cc = 0; cc < 64; cc += CCH) {
        __syncthreads();
        {   // float4 staging of the phi chunk
            const float4* src = reinterpret_cast<const float4*>(phi + ((size_t)n * 64 + cc) * 1024);
            float4* dst = reinterpret_cast<float4*>(pbuf);
            for (int i = tid; i < CCH * 256; i += 256) dst[i] = src[i];
        }
        __syncthreads();
        #pragma unroll
        for (int c = 0; c < CCH; ++c) {
            float ph[16];
            #pragma unroll
            for (int k = 0; k < 16; ++k) ph[k] = pbuf[c * 1024 + k * 64 + lane];
            #pragma unroll
            for (int r = 0; r < RPW; ++r) {
                float th = thl[(cc + c) * ROWS + wv * RPW + r];
                #pragma unroll
                for (int k = 0; k < 16; ++k) acc[r][k] = fmaf(th, ph[k], acc[r][k]);
            }
        }
    }

    // ---- per-row softmax chain: Ra, Rd, S (all f32, in-register) ----
    float d2v[16], d2inv[16];
    #pragma unroll
    for (int k = 0; k < 16; ++k) {
        d2v[k] = d2l[k * 64 + lane];
        d2inv[k] = 1.f / (d2v[k] + EPSF);
    }
    float yscale[RPW];
    #pragma unroll
    for (int r = 0; r < RPW; ++r) {
        float m = -1e30f;
        #pragma unroll
        for (int k = 0; k < 16; ++k) m = fmaxf(m, acc[r][k]);
        m = wave_max(m);
        float sum = 0.f;
        #pragma unroll
        for (int k = 0; k < 16; ++k) { float e = __expf(acc[r][k] - m); acc[r][k] = e; sum += e; }
        sum = wave_sum(sum);
        float inv_ra = 1.f / sum;
        float d1v = d1[n * 4096 + row0 + wv * RPW + r];
        float inv1 = 1.f / (d1v + EPSF);
        float rdl[16];
        float dm = -1e30f;
        #pragma unroll
        for (int k = 0; k < 16; ++k) {
            float v = fminf(d1v * d2inv[k], d2v[k] * inv1);
            rdl[k] = v; dm = fmaxf(dm, v);
        }
        dm = wave_max(dm);
        float dsum = 0.f;
        #pragma unroll
        for (int k = 0; k < 16; ++k) { float e = __expf(rdl[k] - dm); rdl[k] = e; dsum += e; }
        dsum = wave_sum(dsum);
        float inv = inv_ra / dsum;
        float pm = -1e30f;
        #pragma unroll
        for (int k = 0; k < 16; ++k) { float p = acc[r][k] * rdl[k] * inv; acc[r][k] = p; pm = fmaxf(pm, p); }
        pm = wave_max(pm);
        float ss = 0.f;
        #pragma unroll
        for (int k = 0; k < 16; ++k) { float e = __expf(acc[r][k] - pm); acc[r][k] = e; ss += e; }
        ss = wave_sum(ss);
        yscale[r] = 1.f / ss;
    }

    // ---- GEMM2: y[r][c] = sum_j s[r][j] * g[j][c]; s broadcast via readlane,
    //      g streamed from global (L2-resident, coalesced) ----
    const float* gp = g_t + (size_t)n * 1024 * 64 + lane;
    float yacc[RPW] = {0.f, 0.f, 0.f, 0.f};
    #pragma unroll
    for (int k = 0; k < 16; ++k) {
        #pragma unroll 4
        for (int jj = 0; jj < 64; ++jj) {
            float gv = gp[(size_t)(k * 64 + jj) * 64];
            #pragma unroll
            for (int r = 0; r < RPW; ++r)
                yacc[r] = fmaf(lane_bcast(acc[r][k], jj), gv, yacc[r]);
        }
    }
    #pragma unroll
    for (int r = 0; r < RPW; ++r)
        y_t[((size_t)n * 64 + lane) * 4096 + row0 + wv * RPW + r] = yacc[r] * yscale[r];
}

// ---------------- K6: z = conv1x1(y, w_z, b_z) ----------------
__global__ void k_z(const float* __restrict__ y_t, const float* __restrict__ w_z,
                    const float* __restrict__ b_z, float* __restrict__ z) {
    __shared__ float wl[64 * 64];
    int ohalf = blockIdx.z;
    for (int i = threadIdx.x; i < 64 * 64; i += 256)
        wl[i] = w_z[(size_t)(ohalf * 64) * 64 + i];
    __syncthreads();
    int n = blockIdx.y;
    int p = blockIdx.x * 256 + threadIdx.x;
    float acc[64];
    #pragma unroll
    for (int o = 0; o < 64; ++o) acc[o] = b_z[ohalf * 64 + o];
    const float* yp = y_t + (size_t)n * 64 * 4096 + p;
    for (int c = 0; c < 64; ++c) {
        float yv = yp[(size_t)c * 4096];
        #pragma unroll
        for (int o = 0; o < 64; ++o) acc[o] = fmaf(wl[o * 64 + c], yv, acc[o]);
    }
    float* zp = z + ((size_t)n * 128 + ohalf * 64) * 4096 + p;
    #pragma unroll
    for (int o = 0; o < 64; ++o) zp[(size_t)o * 4096] = acc[o];
}

// ---------------- K7: out = x + bilinear_up(z, 64->256) ----------------
__global__ void k_final(const float* __restrict__ x, const float* __restrict__ z,
                        float* __restrict__ out) {
    int idx = blockIdx.x * 256 + threadIdx.x;   // 4*128*256*64 = 8388608 float4s
    int j4 = idx & 63;
    int i  = (idx >> 6) & 255;
    int c  = (idx >> 14) & 127;
    int n  = idx >> 21;
    float fy = (i * 63.f) / 255.f;
    int y0 = (int)floorf(fy); int y1 = min(y0 + 1, 63);
    float wy = fy - (float)y0;
    const float* zp = z + ((size_t)n * 128 + c) * 4096;
    float4 xo = reinterpret_cast<const float4*>(x)[idx];
    float res[4];
    #pragma unroll
    for (int m = 0; m < 4; ++m) {
        int j = j4 * 4 + m;
        float fx = (j * 63.f) / 255.f;
        int x0 = (int)floorf(fx); int x1 = min(x0 + 1, 63);
        float wx = fx - (float)x0;
        float r0 = zp[y0 * 64 + x0] * (1.f - wx) + zp[y0 * 64 + x1] * wx;
        float r1 = zp[y1 * 64 + x0] * (1.f - wx) + zp[y1 * 64 + x1] * wx;
        res[m] = r0 * (1.f - wy) + r1 * wy;
    }
    float4 o;
    o.x = xo.x + res[0]; o.y = xo.y + res[1];
    o.z = xo.z + res[2]; o.w = xo.w + res[3];
    reinterpret_cast<float4*>(out)[idx] = o;
}

// ---------------- launch ----------------
extern "C" void kernel_launch(void* const* d_in, const int* in_sizes, int n_in,
                              void* d_out, int out_size, void* d_ws, size_t ws_size,
                              hipStream_t stream) {
    const float* x       = (const float*)d_in[0];
    const float* depth   = (const float*)d_in[1];
    const float* w_theta = (const float*)d_in[2];
    const float* b_theta = (const float*)d_in[3];
    const float* w_phi   = (const float*)d_in[4];
    const float* b_phi   = (const float*)d_in[5];
    const float* w_g     = (const float*)d_in[6];
    const float* b_g     = (const float*)d_in[7];
    const float* w_down  = (const float*)d_in[8];
    const float* w_z     = (const float*)d_in[9];
    const float* b_z     = (const float*)d_in[10];
    float* out = (float*)d_out;

    float* ws = (float*)d_ws;
    float* xd    = ws;                    // 2097152
    float* theta = xd    + 2097152;       // 1048576
    float* phi_u = theta + 1048576;       // 1048576
    float* g_u   = phi_u + 1048576;       // 1048576
    float* phi   = g_u   + 1048576;       // 262144
    float* g_t   = phi   + 262144;        // 262144
    float* d1    = g_t   + 262144;        // 16384
    float* d2    = d1    + 16384;         // 4096
    float* y_t   = d2    + 4096;          // 1048576
    float* z     = y_t   + 1048576;       // 2097152

    k_down <<<8192, 256, 0, stream>>>(x, w_down, xd);
    k_conv <<<dim3(16, 4, 3), 256, 0, stream>>>(xd, w_theta, b_theta, w_phi, b_phi,
                                                w_g, b_g, theta, phi_u, g_u);
    k_pool <<<dim3(1024, 2), 256, 0, stream>>>(phi_u, g_u, phi, g_t);
    k_d12  <<<80, 256, 0, stream>>>(depth, d1, d2);
    k_attn <<<dim3(256, 4), 256, 0, stream>>>(theta, phi, g_t, d1, d2, y_t);
    k_z    <<<dim3(16, 4, 2), 256, 0, stream>>>(y_t, w_z, b_z, z);
    k_final<<<32768, 256, 0, stream>>>(x, z, out);
}

// Round 8
// 702.136 us; speedup vs baseline: 1.0959x; 1.0959x over previous
//
#include <hip/hip_runtime.h>

#define EPSF 1e-6f

// ---------------- wave helpers ----------------
__device__ __forceinline__ float wave_max(float v) {
    #pragma unroll
    for (int m = 32; m; m >>= 1) v = fmaxf(v, __shfl_xor(v, m, 64));
    return v;
}
__device__ __forceinline__ float wave_sum(float v) {
    #pragma unroll
    for (int m = 32; m; m >>= 1) v += __shfl_xor(v, m, 64);
    return v;
}
__device__ __forceinline__ float lane_bcast(float v, int src) {
    return __int_as_float(__builtin_amdgcn_readlane(__float_as_int(v), src));
}

// ---------------- K1: depthwise 4x4 stride-4 downsample ----------------
// x [4,128,256,256] -> xd [4,128,64,64]
__global__ void k_down(const float* __restrict__ x, const float* __restrict__ wd,
                       float* __restrict__ xd) {
    int idx = blockIdx.x * 256 + threadIdx.x;   // 4*128*64*64 = 2097152
    int ow = idx & 63;
    int oh = (idx >> 6) & 63;
    int c  = (idx >> 12) & 127;
    int n  = idx >> 19;
    const float* xp = x + ((((size_t)n * 128 + c) * 256 + oh * 4) * 256) + ow * 4;
    const float* w  = wd + c * 16;
    float acc = 0.f;
    #pragma unroll
    for (int r = 0; r < 4; ++r) {
        float4 v = *reinterpret_cast<const float4*>(xp + (size_t)r * 256);
        acc += w[r*4+0]*v.x + w[r*4+1]*v.y + w[r*4+2]*v.z + w[r*4+3]*v.w;
    }
    xd[idx] = acc;
}

// ---------------- K2: 1x1 convs (theta / phi_u / g_u) ----------------
// xd [n,128,4096] -> out [n,64,4096];  grid (16 p-blocks, 4 n, 3 which)
// v3: weights read directly (block-uniform -> s_load + SGPR-operand FMA);
//     no LDS, no barrier.
__global__ void k_conv(const float* __restrict__ xd,
                       const float* __restrict__ w0, const float* __restrict__ b0,
                       const float* __restrict__ w1, const float* __restrict__ b1,
                       const float* __restrict__ w2, const float* __restrict__ b2,
                       float* __restrict__ theta, float* __restrict__ phi_u,
                       float* __restrict__ g_u) {
    int which = blockIdx.z;
    const float* w = (which == 0) ? w0 : (which == 1) ? w1 : w2;
    const float* b = (which == 0) ? b0 : (which == 1) ? b1 : b2;
    float* out = (which == 0) ? theta : (which == 1) ? phi_u : g_u;
    int n = blockIdx.y;
    int p = blockIdx.x * 256 + threadIdx.x;
    const float* xp = xd + (size_t)n * 128 * 4096 + p;
    float acc[64];
    #pragma unroll
    for (int o = 0; o < 64; ++o) acc[o] = b[o];
    for (int c = 0; c < 128; ++c) {
        float xv = xp[(size_t)c * 4096];
        #pragma unroll
        for (int o = 0; o < 64; ++o) acc[o] = fmaf(w[o * 128 + c], xv, acc[o]);
    }
    float* op = out + (size_t)n * 64 * 4096 + p;
    #pragma unroll
    for (int o = 0; o < 64; ++o) op[(size_t)o * 4096] = acc[o];
}

// ---------------- K3: 2x2 maxpool (phi stays [c][j]; g transposed to [j][c]) ----------------
__global__ void k_pool(const float* __restrict__ phi_u, const float* __restrict__ g_u,
                       float* __restrict__ phi, float* __restrict__ g_t) {
    int idx = blockIdx.x * 256 + threadIdx.x;   // 4*64*1024 = 262144
    int q = idx & 1023;
    int o = (idx >> 10) & 63;
    int n = idx >> 16;
    int qh = q >> 5, qw = q & 31;
    const float* sel = (blockIdx.y == 0) ? phi_u : g_u;
    const float* sp = sel + (((size_t)n * 64 + o) * 4096) + (qh * 2) * 64 + qw * 2;
    float m = fmaxf(fmaxf(sp[0], sp[1]), fmaxf(sp[64], sp[65]));
    if (blockIdx.y == 0) phi[idx] = m;
    else g_t[((size_t)n * 1024 + q) * 64 + o] = m;
}

// ---------------- K4: bilinear depth samples d1 (64x64), d2 (32x32) ----------------
__global__ void k_d12(const float* __restrict__ depth, float* __restrict__ d1,
                      float* __restrict__ d2) {
    int idx = blockIdx.x * 256 + threadIdx.x;
    const int T1 = 4 * 4096;
    bool is1 = idx < T1;
    int e = is1 ? idx : idx - T1;
    if (!is1 && e >= 4 * 1024) return;
    int n, oh, ow;
    float fy, fx;
    if (is1) { n = e >> 12; oh = (e >> 6) & 63; ow = e & 63;
               fy = (oh * 255.f) / 63.f;  fx = (ow * 255.f) / 63.f; }
    else     { n = e >> 10; oh = (e >> 5) & 31; ow = e & 31;
               fy = (oh * 255.f) / 31.f;  fx = (ow * 255.f) / 31.f; }
    int y0 = (int)floorf(fy); int y1 = min(y0 + 1, 255);
    int x0 = (int)floorf(fx); int x1 = min(x0 + 1, 255);
    float wy = fy - (float)y0, wx = fx - (float)x0;
    const float* dp = depth + (size_t)n * 65536;
    float v00 = dp[y0 * 256 + x0], v01 = dp[y0 * 256 + x1];
    float v10 = dp[y1 * 256 + x0], v11 = dp[y1 * 256 + x1];
    float r0 = v00 * (1.f - wx) + v01 * wx;
    float r1 = v10 * (1.f - wx) + v11 * wx;
    float v  = r0 * (1.f - wy) + r1 * wy;
    if (is1) d1[e] = v; else d2[e] = v;
}

// ---------------- K5: fused attention (v3: register-lean, no spill) ----------------
// theta [n,64,4096], phi [n,64,1024], g_t [n,1024,64], d1 [n,4096], d2 [n,1024]
// -> y_t [n,64,4096]
// 256 thr = 4 waves; 16 rows/block (4/wave); grid (256,4)
// LDS = 32KB phi chunk + 4KB theta + 4KB d2 = 40960 B (4 blocks/CU = 160KiB exactly).
// Register budget: acc[4][16]=64 + d2inv[16]=16 + ~15 scalars ~= 95-110 VGPR.
// R3 lesson: bounds(256,3) gave VGPR=84 -> acc spilled -> 290MB scratch writes.
// v3 removes d2v[16] (reread from LDS) and rdl[16] (recompute pass) so the
// kernel FITS the 128-VGPR cap that 4 blocks/CU implies.
#define ROWS 16
#define RPW  4
#define CCH  8
__global__ __launch_bounds__(256, 4)
void k_attn(const float* __restrict__ theta, const float* __restrict__ phi,
            const float* __restrict__ g_t, const float* __restrict__ d1,
            const float* __restrict__ d2, float* __restrict__ y_t) {
    __shared__ float pbuf[CCH * 1024];   // 32KB phi chunk
    __shared__ float thl[64 * ROWS];     // theta tile [c][r]
    __shared__ float d2l[1024];

    int n = blockIdx.y;
    int row0 = blockIdx.x * ROWS;
    int tid = threadIdx.x;
    int lane = tid & 63;
    int wv = tid >> 6;

    for (int i = tid; i < ROWS * 64; i += 256) {
        int r = i & (ROWS - 1); int c = i >> 4;
        thl[c * ROWS + r] = theta[((size_t)n * 64 + c) * 4096 + row0 + r];
    }
    for (int i = tid; i < 1024; i += 256) d2l[i] = d2[n * 1024 + i];

    float acc[RPW][16];
    #pragma unroll
    for (int r = 0; r < RPW; ++r)
        #pragma unroll
        for (int k = 0; k < 16; ++k) acc[r][k] = 0.f;

    // ---- GEMM1: a[r][j] = theta_row . phi_col ----
    for (int cc = 0; cc < 64; cc += CCH) {
        __syncthreads();
        {   // float4 staging of the phi chunk
            const float4* src = reinterpret_cast<const float4*>(phi + ((size_t)n * 64 + cc) * 1024);
            float4* dst = reinterpret_cast<float4*>(pbuf);
            for (int i = tid; i < CCH * 256; i += 256) dst[i] = src[i];
        }
        __syncthreads();
        #pragma unroll
        for (int c = 0; c < CCH; ++c) {
            float ph[16];
            #pragma unroll
            for (int k = 0; k < 16; ++k) ph[k] = pbuf[c * 1024 + k * 64 + lane];
            #pragma unroll
            for (int r = 0; r < RPW; ++r) {
                float th = thl[(cc + c) * ROWS + wv * RPW + r];
                #pragma unroll
                for (int k = 0; k < 16; ++k) acc[r][k] = fmaf(th, ph[k], acc[r][k]);
            }
        }
    }

    // ---- per-row softmax chain: Ra, Rd, S (register-lean) ----
    float d2inv[16];
    #pragma unroll
    for (int k = 0; k < 16; ++k) d2inv[k] = 1.f / (d2l[k * 64 + lane] + EPSF);

    float yscale[RPW];
    #pragma unroll
    for (int r = 0; r < RPW; ++r) {
        // softmax(Ra): acc -> unnormalized exp, inv_ra = 1/sum
        float m = -1e30f;
        #pragma unroll
        for (int k = 0; k < 16; ++k) m = fmaxf(m, acc[r][k]);
        m = wave_max(m);
        float sum = 0.f;
        #pragma unroll
        for (int k = 0; k < 16; ++k) { float e = __expf(acc[r][k] - m); acc[r][k] = e; sum += e; }
        sum = wave_sum(sum);
        float inv_ra = 1.f / sum;
        // Rd logits: pass 1 = max only (no array)
        float d1v = d1[n * 4096 + row0 + wv * RPW + r];
        float inv1 = 1.f / (d1v + EPSF);
        float dm = -1e30f;
        #pragma unroll
        for (int k = 0; k < 16; ++k) {
            float v = fminf(d1v * d2inv[k], d2l[k * 64 + lane] * inv1);
            dm = fmaxf(dm, v);
        }
        dm = wave_max(dm);
        // pass 2: recompute logit, exp, fold product Ra_e*Rd_e into acc
        float dsum = 0.f, um = -1e30f;
        #pragma unroll
        for (int k = 0; k < 16; ++k) {
            float v = fminf(d1v * d2inv[k], d2l[k * 64 + lane] * inv1);
            float re = __expf(v - dm);
            dsum += re;
            float t = acc[r][k] * re;
            acc[r][k] = t;
            um = fmaxf(um, t);
        }
        dsum = wave_sum(dsum);
        um = wave_max(um);
        float inv = inv_ra / dsum;   // p_k = t_k * inv  (true Ra*Rd product)
        float pm = um * inv;         // max_k p_k  (inv > 0)
        // softmax(Ra*Rd): unnormalized exp into acc, scale at write
        float ss = 0.f;
        #pragma unroll
        for (int k = 0; k < 16; ++k) {
            float e = __expf(acc[r][k] * inv - pm);
            acc[r][k] = e; ss += e;
        }
        ss = wave_sum(ss);
        yscale[r] = 1.f / ss;
    }

    // ---- GEMM2: y[r][c] = sum_j s[r][j] * g[j][c]; s broadcast via readlane,
    //      g streamed from global (L2-resident, coalesced) ----
    const float* gp = g_t + (size_t)n * 1024 * 64 + lane;
    float yacc[RPW] = {0.f, 0.f, 0.f, 0.f};
    #pragma unroll
    for (int k = 0; k < 16; ++k) {
        #pragma unroll 4
        for (int jj = 0; jj < 64; ++jj) {
            float gv = gp[(size_t)(k * 64 + jj) * 64];
            #pragma unroll
            for (int r = 0; r < RPW; ++r)
                yacc[r] = fmaf(lane_bcast(acc[r][k], jj), gv, yacc[r]);
        }
    }
    #pragma unroll
    for (int r = 0; r < RPW; ++r)
        y_t[((size_t)n * 64 + lane) * 4096 + row0 + wv * RPW + r] = yacc[r] * yscale[r];
}

// ---------------- K6: z = conv1x1(y, w_z, b_z) ----------------
__global__ void k_z(const float* __restrict__ y_t, const float* __restrict__ w_z,
                    const float* __restrict__ b_z, float* __restrict__ z) {
    int ohalf = blockIdx.z;
    int n = blockIdx.y;
    int p = blockIdx.x * 256 + threadIdx.x;
    float acc[64];
    #pragma unroll
    for (int o = 0; o < 64; ++o) acc[o] = b_z[ohalf * 64 + o];
    const float* yp = y_t + (size_t)n * 64 * 4096 + p;
    const float* w = w_z + (size_t)(ohalf * 64) * 64;
    for (int c = 0; c < 64; ++c) {
        float yv = yp[(size_t)c * 4096];
        #pragma unroll
        for (int o = 0; o < 64; ++o) acc[o] = fmaf(w[o * 64 + c], yv, acc[o]);
    }
    float* zp = z + ((size_t)n * 128 + ohalf * 64) * 4096 + p;
    #pragma unroll
    for (int o = 0; o < 64; ++o) zp[(size_t)o * 4096] = acc[o];
}

// ---------------- K7: out = x + bilinear_up(z, 64->256) ----------------
__global__ void k_final(const float* __restrict__ x, const float* __restrict__ z,
                        float* __restrict__ out) {
    int idx = blockIdx.x * 256 + threadIdx.x;   // 4*128*256*64 = 8388608 float4s
    int j4 = idx & 63;
    int i  = (idx >> 6) & 255;
    int c  = (idx >> 14) & 127;
    int n  = idx >> 21;
    float fy = (i * 63.f) / 255.f;
    int y0 = (int)floorf(fy); int y1 = min(y0 + 1, 63);
    float wy = fy - (float)y0;
    const float* zp = z + ((size_t)n * 128 + c) * 4096;
    float4 xo = reinterpret_cast<const float4*>(x)[idx];
    float res[4];
    #pragma unroll
    for (int m = 0; m < 4; ++m) {
        int j = j4 * 4 + m;
        float fx = (j * 63.f) / 255.f;
        int x0 = (int)floorf(fx); int x1 = min(x0 + 1, 63);
        float wx = fx - (float)x0;
        float r0 = zp[y0 * 64 + x0] * (1.f - wx) + zp[y0 * 64 + x1] * wx;
        float r1 = zp[y1 * 64 + x0] * (1.f - wx) + zp[y1 * 64 + x1] * wx;
        res[m] = r0 * (1.f - wy) + r1 * wy;
    }
    float4 o;
    o.x = xo.x + res[0]; o.y = xo.y + res[1];
    o.z = xo.z + res[2]; o.w = xo.w + res[3];
    reinterpret_cast<float4*>(out)[idx] = o;
}

// ---------------- launch ----------------
extern "C" void kernel_launch(void* const* d_in, const int* in_sizes, int n_in,
                              void* d_out, int out_size, void* d_ws, size_t ws_size,
                              hipStream_t stream) {
    const float* x       = (const float*)d_in[0];
    const float* depth   = (const float*)d_in[1];
    const float* w_theta = (const float*)d_in[2];
    const float* b_theta = (const float*)d_in[3];
    const float* w_phi   = (const float*)d_in[4];
    const float* b_phi   = (const float*)d_in[5];
    const float* w_g     = (const float*)d_in[6];
    const float* b_g     = (const float*)d_in[7];
    const float* w_down  = (const float*)d_in[8];
    const float* w_z     = (const float*)d_in[9];
    const float* b_z     = (const float*)d_in[10];
    float* out = (float*)d_out;

    float* ws = (float*)d_ws;
    float* xd    = ws;                    // 2097152
    float* theta = xd    + 2097152;       // 1048576
    float* phi_u = theta + 1048576;       // 1048576
    float* g_u   = phi_u + 1048576;       // 1048576
    float* phi   = g_u   + 1048576;       // 262144
    float* g_t   = phi   + 262144;        // 262144
    float* d1    = g_t   + 262144;        // 16384
    float* d2    = d1    + 16384;         // 4096
    float* y_t   = d2    + 4096;          // 1048576
    float* z     = y_t   + 1048576;       // 2097152

    k_down <<<8192, 256, 0, stream>>>(x, w_down, xd);
    k_conv <<<dim3(16, 4, 3), 256, 0, stream>>>(xd, w_theta, b_theta, w_phi, b_phi,
                                                w_g, b_g, theta, phi_u, g_u);
    k_pool <<<dim3(1024, 2), 256, 0, stream>>>(phi_u, g_u, phi, g_t);
    k_d12  <<<80, 256, 0, stream>>>(depth, d1, d2);
    k_attn <<<dim3(256, 4), 256, 0, stream>>>(theta, phi, g_t, d1, d2, y_t);
    k_z    <<<dim3(16, 4, 2), 256, 0, stream>>>(y_t, w_z, b_z, z);
    k_final<<<32768, 256, 0, stream>>>(x, z, out);
}